// Round 5
// baseline (391.441 us; speedup 1.0000x reference)
//
#include <hip/hip_runtime.h>
#include <stdint.h>

typedef unsigned short u16;
typedef unsigned int   u32;
typedef __attribute__((ext_vector_type(8))) short bf16x8;
typedef __attribute__((ext_vector_type(4))) float f32x4;

static constexpr float kScale = 0.17677669529663687f; // HD^-0.5

// ---------- bf16 helpers (bf16 carried as u16) ----------
__device__ __forceinline__ float bfl(u32 dw){ union{u32 u; float f;} x; x.u = dw << 16;        return x.f; }
__device__ __forceinline__ float bfh(u32 dw){ union{u32 u; float f;} x; x.u = dw & 0xffff0000u; return x.f; }
__device__ __forceinline__ float bf2f(u16 v){ union{u32 u; float f;} x; x.u = ((u32)v) << 16;  return x.f; }
__device__ __forceinline__ u16  f2bf(float f){
  union{float f; u32 u;} x; x.f = f;
  u32 r = x.u + 0x7fffu + ((x.u >> 16) & 1u);  // RNE
  return (u16)(r >> 16);
}

// ---------------------------------------------------------------------------
// D0: dtype detect. flag=1 means "inputs are f32".
// ---------------------------------------------------------------------------
__global__ void detect_kernel(const u16* __restrict__ bias, int* __restrict__ flag){
  int tid = threadIdx.x;               // 64 threads
  u16 raw = bias[tid * 2];
  int big = (fabsf(bf2f(raw)) > 1e6f) ? 1 : 0;
  if ((raw & 0x7F80u) == 0x7F80u) big = 1;   // NaN/Inf bit pattern
  #pragma unroll
  for (int m = 1; m < 64; m <<= 1) big |= __shfl_xor(big, m);
  if (tid == 0) *flag = big;
}

// ---------------------------------------------------------------------------
// P0: pre-convert all weights to bf16 once.
// Wbf rows 0..1279 = in_proj_weight, rows 1280..1535 = out_proj_weight.
// ---------------------------------------------------------------------------
__global__ __launch_bounds__(256) void prep_weights_kernel(
    const void* __restrict__ in_w, const void* __restrict__ out_w,
    u16* __restrict__ Wbf, const int* __restrict__ flag){
  const bool isf32 = (*flag != 0);
  int idx = blockIdx.x * 256 + threadIdx.x;       // 192 blocks -> 49152 thr
  size_t off = (size_t)idx * 8;                   // 393216 elems total
  const size_t IN_ELEMS = (size_t)1280 * 256;
  bool isout = off >= IN_ELEMS;
  const void* src = isout ? out_w : in_w;
  size_t soff = isout ? off - IN_ELEMS : off;
  u16 xl[8];
  if (isf32){
    const float* p = (const float*)src + soff;
    float4 f0 = *(const float4*)p;
    float4 f1 = *(const float4*)(p + 4);
    xl[0]=f2bf(f0.x); xl[1]=f2bf(f0.y); xl[2]=f2bf(f0.z); xl[3]=f2bf(f0.w);
    xl[4]=f2bf(f1.x); xl[5]=f2bf(f1.y); xl[6]=f2bf(f1.z); xl[7]=f2bf(f1.w);
  } else {
    *(uint4*)xl = *(const uint4*)((const u16*)src + soff);
  }
  *(uint4*)(Wbf + off) = *(uint4*)xl;
}

// ---------------------------------------------------------------------------
// K0 v2: row/col means. 768 blocks (2 rows/block, float2/thread).
// ---------------------------------------------------------------------------
__global__ __launch_bounds__(256) void means_kernel(
    const void* __restrict__ key_row, const void* __restrict__ key_col,
    float* __restrict__ krm, float* __restrict__ kcm,
    const int* __restrict__ flag){
  const bool isf32 = (*flag != 0);
  int tid = threadIdx.x;
  int r2  = tid >> 7;               // 0..1 row within block
  int cc  = (tid & 127) * 2;        // even column 0..254
  int row = blockIdx.x * 2 + r2;    // 0..767  (= n*96 + rw)
  int n   = row / 96;
  int rw  = row - n*96;

  size_t base, stride;
  const void* src;
  float* dst;
  if (blockIdx.y == 0){         // krm: mean over h; rw = w
    src    = key_row;
    base   = ((size_t)(n*96)*96 + rw)*256 + cc;
    stride = (size_t)96*256;
    dst    = krm + (size_t)row*256 + cc;
  } else {                      // kcm: mean over w; rw = h
    src    = key_col;
    base   = ((size_t)(n*96) + rw)*(size_t)(96*256) + cc;
    stride = 256;
    dst    = kcm + (size_t)row*256 + cc;
  }

  float a0 = 0.f, a1 = 0.f;
  if (isf32){
    const float* p = (const float*)src + base;
    #pragma unroll 4
    for (int t = 0; t < 96; t++){
      float2 f = *(const float2*)(p + t*stride);
      a0 += f.x; a1 += f.y;
    }
  } else {
    const u16* p = (const u16*)src + base;
    #pragma unroll 4
    for (int t = 0; t < 96; t++){
      u32 u = *(const u32*)(p + t*stride);
      a0 += bfl(u); a1 += bfh(u);
    }
  }
  dst[0] = a0 * (1.f/96.f);
  dst[1] = a1 * (1.f/96.f);
}

// ---------------------------------------------------------------------------
// K1 (MFMA, round-2 proven): Y[m][j] = scale*(sum_k X[m][k]*W[j][k] + b[j]).
// Tile 64x64, 4 waves, 8 K-chunks, single-buffer LDS, 2 barriers/chunk.
// W staged from pre-converted bf16 Wbf (pure uint4 copy).
// XF: 0 = X ws f32, 1 = X ws bf16, 2 = X raw input (dtype per flag).
// OBF: 0 f32 out, 1 bf16 out, 2 dtype-per-flag out.
// OMAP 0: row-major; 1: out-proj remap; 3: v-proj transposed slab (hg=1 path)
// ---------------------------------------------------------------------------
template<int XF, int OBF, int OMAP>
__global__ __launch_bounds__(256) void mfma_proj3(
    const void* __restrict__ Xv0, const void* __restrict__ Xv1,
    const u16* __restrict__ Wbf, int wr00, int wr01,
    const void* __restrict__ Bv, int bo0, int bo1,
    void* __restrict__ Yv0, void* __restrict__ Yv1,
    int M, float scale, int head0, int hg,
    const int* __restrict__ flag){
  const bool isf32 = (*flag != 0);
  const bool xf32  = (XF == 0) || (XF == 2 && isf32);
  __shared__ __align__(16) u16 Xs[64*40];     // 5120 B, stride 40 u16 (80 B)
  __shared__ __align__(16) u16 Ws[64*40];
  __shared__ __align__(16) u16 stile[(OMAP==3) ? 64*66 : 64];

  const void* Xv  = blockIdx.z ? Xv1 : Xv0;
  const int wrow0 = blockIdx.z ? wr01 : wr00;
  const int boff  = blockIdx.z ? bo1  : bo0;
  void* Yv        = blockIdx.z ? Yv1 : Yv0;

  int tid = threadIdx.x;
  int m0  = blockIdx.x * 64;
  int j0  = blockIdx.y * 64;
  int wv  = tid >> 6;
  int ln  = tid & 63;
  int l15 = ln & 15;
  int quad = ln >> 4;
  int mh  = wv & 1;
  int nh  = wv >> 1;

  int srow = tid >> 2;          // 0..63 staging row
  int sko  = (tid & 3) * 8;     // 0,8,16,24

  f32x4 acc[2][2] = {{{0.f,0.f,0.f,0.f},{0.f,0.f,0.f,0.f}},
                     {{0.f,0.f,0.f,0.f},{0.f,0.f,0.f,0.f}}};

  int gm = m0 + srow;
  int wrel = j0 + srow;
  if (OMAP == 3){ wrel += head0*32; if (wrel > 255) wrel = 255; }
  const u16* wsrc = Wbf + (size_t)(wrow0 + wrel)*256 + sko;

  for (int p = 0; p < 8; p++){
    int k0 = p * 32;
    u16 xl[8];
    if (gm < M){
      size_t xoff = (size_t)gm*256 + k0 + sko;
      if (xf32){
        const float* xp = (const float*)Xv + xoff;
        float4 f0 = *(const float4*)xp;
        float4 f1 = *(const float4*)(xp + 4);
        xl[0]=f2bf(f0.x); xl[1]=f2bf(f0.y); xl[2]=f2bf(f0.z); xl[3]=f2bf(f0.w);
        xl[4]=f2bf(f1.x); xl[5]=f2bf(f1.y); xl[6]=f2bf(f1.z); xl[7]=f2bf(f1.w);
      } else {
        *(uint4*)xl = *(const uint4*)((const u16*)Xv + xoff);
      }
    } else {
      #pragma unroll
      for (int i = 0; i < 8; i++) xl[i] = 0;
    }
    uint4 wl = *(const uint4*)(wsrc + k0);     // bf16 W: pure copy
    __syncthreads();
    *(uint4*)(Xs + srow*40 + sko) = *(uint4*)xl;
    *(uint4*)(Ws + srow*40 + sko) = wl;
    __syncthreads();

    bf16x8 a0 = *(const bf16x8*)(Xs + (mh*32 +      l15)*40 + quad*8);
    bf16x8 a1 = *(const bf16x8*)(Xs + (mh*32 + 16 + l15)*40 + quad*8);
    bf16x8 b0 = *(const bf16x8*)(Ws + (nh*32 +      l15)*40 + quad*8);
    bf16x8 b1 = *(const bf16x8*)(Ws + (nh*32 + 16 + l15)*40 + quad*8);
    acc[0][0] = __builtin_amdgcn_mfma_f32_16x16x32_bf16(a0, b0, acc[0][0], 0,0,0);
    acc[0][1] = __builtin_amdgcn_mfma_f32_16x16x32_bf16(a0, b1, acc[0][1], 0,0,0);
    acc[1][0] = __builtin_amdgcn_mfma_f32_16x16x32_bf16(a1, b0, acc[1][0], 0,0,0);
    acc[1][1] = __builtin_amdgcn_mfma_f32_16x16x32_bf16(a1, b1, acc[1][1], 0,0,0);
  }

  // bias per tj (col depends only on tj, l15)
  float bv[2];
  #pragma unroll
  for (int tj = 0; tj < 2; tj++){
    int bidx = j0 + nh*32 + tj*16 + l15;
    if (OMAP == 3 && bidx > hg*32 - 1) bidx = hg*32 - 1;  // clamped never stored
    bv[tj] = isf32 ? ((const float*)Bv)[boff + bidx] : bf2f(((const u16*)Bv)[boff + bidx]);
  }

  if (OMAP == 3){
    __syncthreads();
    #pragma unroll
    for (int ti = 0; ti < 2; ti++)
      #pragma unroll
      for (int tj = 0; tj < 2; tj++)
        #pragma unroll
        for (int reg = 0; reg < 4; reg++)
          stile[(mh*32 + ti*16 + quad*4 + reg)*66 + nh*32 + tj*16 + l15] =
              f2bf(scale * (acc[ti][tj][reg] + bv[tj]));
    __syncthreads();
    int hw_i = tid & 63;
    int m    = m0 + hw_i;
    int nn   = m / 9216;
    int hwin = m - nn*9216;
    int hh   = hwin / 96, ww = hwin - hh*96;
    #pragma unroll
    for (int e = 0; e < 16; e++){
      int d_col = (tid >> 6) * 16 + e;   // 0..63
      int col   = j0 + d_col;
      if (col < hg*32){
        int gsv = nn*hg + (col >> 5), d = col & 31;
        ((u16*)Yv)[ (((size_t)gsv*96 + hh)*32 + d)*96 + ww ] = stile[hw_i*66 + d_col];
      }
    }
    return;
  }

  #pragma unroll
  for (int ti = 0; ti < 2; ti++)
    #pragma unroll
    for (int tj = 0; tj < 2; tj++)
      #pragma unroll
      for (int reg = 0; reg < 4; reg++){
        int m = m0 + mh*32 + ti*16 + quad*4 + reg;
        if (m >= M) continue;
        int col = j0 + nh*32 + tj*16 + l15;
        float vval = scale * (acc[ti][tj][reg] + bv[tj]);
        int orow = (OMAP == 1) ? ((m % 300)*8 + (m / 300)) : m;
        size_t oidx = (size_t)orow*256 + col;
        if (OBF == 2){
          if (isf32) ((float*)Yv)[oidx] = vval; else ((u16*)Yv)[oidx] = f2bf(vval);
        } else if (OBF == 1) ((u16*)Yv)[oidx] = f2bf(vval);
        else                 ((float*)Yv)[oidx] = vval;
      }
}

// ---------------------------------------------------------------------------
// K1v (MFMA v-proj, NJ j-tiles per block): each block stages X ONCE per chunk
// and W for ALL NJ*64 output cols -> X (75.5 MB f32) read/converted exactly
// once (was 4x). Same single-buffer, 2-barriers-per-chunk schedule as
// mfma_proj3 (proven TLP-friendly). NJ*64 == hg*32 output cols.
// LDS: Xs 5.1KB + Ws 20.5KB (NJ=4, stile aliased) = 25.6KB -> 6 blocks/CU.
// ---------------------------------------------------------------------------
template<int NJ>
__global__ __launch_bounds__(256) void vproj_kernel(
    const void* __restrict__ Xv, const u16* __restrict__ Wbf, int wbase,
    const void* __restrict__ Bv, int boff, u16* __restrict__ Yv,
    int hg, const int* __restrict__ flag){
  const bool xf32 = (*flag != 0);
  constexpr int WS_ELE = (NJ*64*40 > 64*66) ? NJ*64*40 : 64*66;
  __shared__ __align__(16) u16 Xs[64*40];
  __shared__ __align__(16) u16 Ws[WS_ELE];   // stile aliases this after loop
  u16* stile = Ws;

  int tid = threadIdx.x;
  int m0  = blockIdx.x * 64;
  int wv  = tid >> 6;
  int ln  = tid & 63;
  int l15 = ln & 15;
  int quad = ln >> 4;
  int mh  = wv & 1;
  int nh  = wv >> 1;

  int srow = tid >> 2;          // 0..63
  int sko  = (tid & 3) * 8;     // 0,8,16,24

  f32x4 acc[NJ][2][2];
  #pragma unroll
  for (int jt = 0; jt < NJ; jt++)
    #pragma unroll
    for (int i = 0; i < 2; i++)
      #pragma unroll
      for (int j = 0; j < 2; j++)
        acc[jt][i][j] = (f32x4){0.f,0.f,0.f,0.f};

  const int gm = m0 + srow;            // M = 73728 = 1152*64, always valid
  const size_t xrow = (size_t)gm*256 + sko;
  const u16* wsrc = Wbf + (size_t)(wbase + srow)*256 + sko;

  for (int p = 0; p < 8; p++){
    const int k0 = p * 32;
    u16 xl[8];
    if (xf32){
      const float* xp = (const float*)Xv + xrow + k0;
      float4 f0 = *(const float4*)xp;
      float4 f1 = *(const float4*)(xp + 4);
      xl[0]=f2bf(f0.x); xl[1]=f2bf(f0.y); xl[2]=f2bf(f0.z); xl[3]=f2bf(f0.w);
      xl[4]=f2bf(f1.x); xl[5]=f2bf(f1.y); xl[6]=f2bf(f1.z); xl[7]=f2bf(f1.w);
    } else {
      *(uint4*)xl = *(const uint4*)((const u16*)Xv + xrow + k0);
    }
    uint4 wl[NJ];
    #pragma unroll
    for (int it = 0; it < NJ; it++)
      wl[it] = *(const uint4*)(wsrc + (size_t)it*64*256 + k0);
    __syncthreads();
    *(uint4*)(Xs + srow*40 + sko) = *(uint4*)xl;
    #pragma unroll
    for (int it = 0; it < NJ; it++)
      *(uint4*)(Ws + (it*64 + srow)*40 + sko) = wl[it];
    __syncthreads();

    bf16x8 a0 = *(const bf16x8*)(Xs + (mh*32 +      l15)*40 + quad*8);
    bf16x8 a1 = *(const bf16x8*)(Xs + (mh*32 + 16 + l15)*40 + quad*8);
    #pragma unroll
    for (int jt = 0; jt < NJ; jt++){
      bf16x8 b0 = *(const bf16x8*)(Ws + (jt*64 + nh*32 +      l15)*40 + quad*8);
      bf16x8 b1 = *(const bf16x8*)(Ws + (jt*64 + nh*32 + 16 + l15)*40 + quad*8);
      acc[jt][0][0] = __builtin_amdgcn_mfma_f32_16x16x32_bf16(a0, b0, acc[jt][0][0], 0,0,0);
      acc[jt][0][1] = __builtin_amdgcn_mfma_f32_16x16x32_bf16(a0, b1, acc[jt][0][1], 0,0,0);
      acc[jt][1][0] = __builtin_amdgcn_mfma_f32_16x16x32_bf16(a1, b0, acc[jt][1][0], 0,0,0);
      acc[jt][1][1] = __builtin_amdgcn_mfma_f32_16x16x32_bf16(a1, b1, acc[jt][1][1], 0,0,0);
    }
  }

  const bool isf32 = xf32;
  int hw_i = ln;
  int m    = m0 + hw_i;
  int nn   = m / 9216;
  int hwin = m - nn*9216;
  int hh   = hwin / 96, ww = hwin - hh*96;

  #pragma unroll
  for (int jt = 0; jt < NJ; jt++){
    float bv[2];
    #pragma unroll
    for (int tj = 0; tj < 2; tj++){
      int col = jt*64 + nh*32 + tj*16 + l15;       // < NJ*64 == hg*32, valid
      bv[tj] = isf32 ? ((const float*)Bv)[boff + col] : bf2f(((const u16*)Bv)[boff + col]);
    }
    __syncthreads();   // protects prior pass's scatter reads / Ws reads
    #pragma unroll
    for (int ti = 0; ti < 2; ti++)
      #pragma unroll
      for (int tj = 0; tj < 2; tj++)
        #pragma unroll
        for (int reg = 0; reg < 4; reg++)
          stile[(mh*32 + ti*16 + quad*4 + reg)*66 + nh*32 + tj*16 + l15] =
              f2bf(acc[jt][ti][tj][reg] + bv[tj]);
    __syncthreads();
    #pragma unroll
    for (int e = 0; e < 16; e++){
      int d_col = wv*16 + e;             // 0..63
      int col   = jt*64 + d_col;         // < hg*32
      int gsv = nn*hg + (col >> 5), d = col & 31;
      Yv[ (((size_t)gsv*96 + hh)*32 + d)*96 + ww ] = stile[hw_i*66 + d_col];
    }
  }
}

// ---------------------------------------------------------------------------
// K2: attention weights. Single-wave blocks; grid (10 l-tiles x 30, gs, rc).
// ---------------------------------------------------------------------------
__global__ __launch_bounds__(64) void attn_weights_kernel(
    const u16* __restrict__ qr, const float* __restrict__ kr,
    const u16* __restrict__ qc, const float* __restrict__ kc,
    u16* __restrict__ arow, u16* __restrict__ acol,
    int head0, int hg){
  __shared__ float qs[30*32];
  int lt = blockIdx.x;                 // 0..9
  int gs = blockIdx.y;                 // n*hg + hr
  int n  = gs / hg;
  int head = head0 + (gs % hg);
  const u16*   q = blockIdx.z ? qc : qr;
  const float* k = blockIdx.z ? kc : kr;
  u16*         a = blockIdx.z ? acol : arow;
  int lane = threadIdx.x;
  int l0   = lt * 30;

  for (int i = lane; i < 960; i += 64){
    int li = i >> 5, d = i & 31;
    qs[i] = bf2f(q[((size_t)(n*300) + l0 + li)*256 + head*32 + d]);
  }

  bool has2 = (lane < 32);
  float k1[32], k2[32];
  {
    const float* kp = k + ((size_t)(n*96) + lane)*256 + head*32;
    #pragma unroll
    for (int d4 = 0; d4 < 8; d4++){
      float4 f = *(const float4*)(kp + d4*4);
      k1[d4*4+0]=f.x; k1[d4*4+1]=f.y; k1[d4*4+2]=f.z; k1[d4*4+3]=f.w;
    }
    int w2c = has2 ? (64 + lane) : 95;
    const float* kp2 = k + ((size_t)(n*96) + w2c)*256 + head*32;
    #pragma unroll
    for (int d4 = 0; d4 < 8; d4++){
      float4 f = *(const float4*)(kp2 + d4*4);
      k2[d4*4+0]=f.x; k2[d4*4+1]=f.y; k2[d4*4+2]=f.z; k2[d4*4+3]=f.w;
    }
  }
  __syncthreads();

  for (int li = 0; li < 30; li++){
    const float* qv = qs + li*32;
    float s1 = 0.f, s2 = 0.f;
    #pragma unroll
    for (int d4 = 0; d4 < 8; d4++){
      float4 f = *(const float4*)(qv + d4*4);
      s1 += f.x*k1[d4*4+0] + f.y*k1[d4*4+1] + f.z*k1[d4*4+2] + f.w*k1[d4*4+3];
      s2 += f.x*k2[d4*4+0] + f.y*k2[d4*4+1] + f.z*k2[d4*4+2] + f.w*k2[d4*4+3];
    }
    float m = fmaxf(s1, has2 ? s2 : -1e30f);
    #pragma unroll
    for (int mask = 1; mask < 64; mask <<= 1) m = fmaxf(m, __shfl_xor(m, mask));
    float e1 = __expf(s1 - m);
    float e2 = has2 ? __expf(s2 - m) : 0.f;
    float s  = e1 + e2;
    #pragma unroll
    for (int mask = 1; mask < 64; mask <<= 1) s += __shfl_xor(s, mask);
    float inv = 1.f / s;
    u16* dst = a + ((size_t)gs*300 + l0 + li)*96;
    dst[lane] = f2bf(e1 * inv);
    if (has2) dst[64 + lane] = f2bf(e2 * inv);
  }
}

// ---------------------------------------------------------------------------
// K3 (MFMA): attn[n][l][head*32+d] = sum_h acol[l,h] * (sum_w arow[l,w] V[h,w,d])
// Vt bf16 [gs][h(96)][d(32)][w(96)]. attn output bf16.
// ---------------------------------------------------------------------------
__global__ __launch_bounds__(256) void rcda_core_kernel(
    const u16* __restrict__ arow, const u16* __restrict__ acol,
    const u16* __restrict__ v, u16* __restrict__ attn, int head0, int hg){
  __shared__ __align__(16) u16 vt[4*32*104];   // 26624 B, w-stride 104
  __shared__ __align__(16) u16 aw[32*96];      // 6144 B
  __shared__ float cs[32*97];                  // 12416 B
  __shared__ float red[2*64*8];                // 4096 B

  int b   = blockIdx.x;
  int xcd = b & 7;
  int jj  = b >> 3;
  int lt  = jj % 10;
  int gg  = jj / 10;
  int gs  = gg*8 + xcd;
  int n   = gs / hg;
  int head = head0 + (gs % hg);
  int l0  = lt * 32;
  int tid = threadIdx.x;
  int wv  = tid >> 6;
  int ln  = tid & 63;
  int l15 = ln & 15;
  int quad = ln >> 4;
  int nt  = wv & 1;
  int hp  = wv >> 1;

  for (int i = tid; i < 384; i += 256){
    int row = i / 12, rem = i - row*12;
    int lc = l0 + row; if (lc > 299) lc = 299;
    *(uint4*)(aw + row*96 + rem*8) = *(const uint4*)(arow + ((size_t)gs*300 + lc)*96 + rem*8);
  }
  for (int i = tid; i < 3072; i += 256){
    int row = i / 96, col = i - row*96;
    int lc = l0 + row; if (lc > 299) lc = 299;
    cs[row*97 + col] = bf2f(acol[((size_t)gs*300 + lc)*96 + col]);
  }
  __syncthreads();

  bf16x8 afr[2][3];
  #pragma unroll
  for (int mt = 0; mt < 2; mt++)
    #pragma unroll
    for (int ks = 0; ks < 3; ks++)
      afr[mt][ks] = *(const bf16x8*)(aw + (mt*16 + l15)*96 + ks*32 + quad*8);

  f32x4 out[2] = {{0.f,0.f,0.f,0.f},{0.f,0.f,0.f,0.f}};
  const u16* vbase = v + (size_t)gs * 96*32*96;

  for (int cc = 0; cc < 24; cc++){
    __syncthreads();
    const uint4* gsrc = (const uint4*)(vbase + (size_t)cc * 4*32*96);
    #pragma unroll
    for (int it = 0; it < 6; it++){
      int i = tid + it*256;
      int row = i / 12, rem = i - row*12;
      *(uint4*)((char*)vt + row*208 + rem*16) = gsrc[i];
    }
    __syncthreads();

    #pragma unroll
    for (int hh = 0; hh < 2; hh++){
      int h = hp*2 + hh;
      bf16x8 bfr[3];
      #pragma unroll
      for (int ks = 0; ks < 3; ks++)
        bfr[ks] = *(const bf16x8*)(vt + (h*32 + nt*16 + l15)*104 + ks*32 + quad*8);
      int habs = cc*4 + h;
      #pragma unroll
      for (int mt = 0; mt < 2; mt++){
        f32x4 t = {0.f,0.f,0.f,0.f};
        t = __builtin_amdgcn_mfma_f32_16x16x32_bf16(afr[mt][0], bfr[0], t, 0,0,0);
        t = __builtin_amdgcn_mfma_f32_16x16x32_bf16(afr[mt][1], bfr[1], t, 0,0,0);
        t = __builtin_amdgcn_mfma_f32_16x16x32_bf16(afr[mt][2], bfr[2], t, 0,0,0);
        #pragma unroll
        for (int reg = 0; reg < 4; reg++){
          float sc = cs[(mt*16 + quad*4 + reg)*97 + habs];
          out[mt][reg] += sc * t[reg];
        }
      }
    }
  }

  __syncthreads();
  if (hp == 1){
    float* r = red + ((size_t)(nt*64 + ln))*8;
    #pragma unroll
    for (int mt = 0; mt < 2; mt++)
      #pragma unroll
      for (int reg = 0; reg < 4; reg++) r[mt*4 + reg] = out[mt][reg];
  }
  __syncthreads();
  if (hp == 0){
    const float* r = red + ((size_t)(nt*64 + ln))*8;
    #pragma unroll
    for (int mt = 0; mt < 2; mt++){
      #pragma unroll
      for (int reg = 0; reg < 4; reg++){
        int l = l0 + mt*16 + quad*4 + reg;
        if (l < 300)
          attn[((size_t)(n*300) + l)*256 + head*32 + nt*16 + l15] =
              f2bf(out[mt][reg] + r[mt*4 + reg]);
      }
    }
  }
}

// ---------------------------------------------------------------------------
// Workspace: flag(256B) | Vt_slab | arow | acol | Wbf | qr | qc | krm | kcm |
//            kr | kc | attn_bf16
// need(hg) = hg*5,640,192 + 7,618,816 bytes
// ---------------------------------------------------------------------------
extern "C" void kernel_launch(void* const* d_in, const int* in_sizes, int n_in,
                              void* d_out, int out_size, void* d_ws, size_t ws_size,
                              hipStream_t stream){
  const void* query_row = d_in[0];
  const void* query_col = d_in[1];
  const void* key_row   = d_in[2];
  const void* key_col   = d_in[3];
  const void* value     = d_in[4];
  const void* in_w      = d_in[5];
  const void* in_b      = d_in[6];
  const void* out_w     = d_in[7];
  const void* out_b     = d_in[8];

  int hg = 1;
  {
    const size_t fixed = 7618816, per = 5640192;
    if      (ws_size >= fixed + 8*per) hg = 8;
    else if (ws_size >= fixed + 4*per) hg = 4;
    else if (ws_size >= fixed + 2*per) hg = 2;
    else                               hg = 1;
  }

  char* ws = (char*)d_ws;
  int*  flag = (int*)ws;
  size_t SV = (size_t)hg * 8 * 9216 * 32 * 2;  // Vt slab bf16
  size_t SA = (size_t)hg * 8 * 300 * 96 * 2;   // a slab bf16
  size_t off = 256;
  u16*   v_slab = (u16*)(ws + off); off += SV;
  u16*   arow   = (u16*)(ws + off); off += SA;
  u16*   acol   = (u16*)(ws + off); off += SA;
  u16*   Wbf    = (u16*)(ws + off); off += 786432;   // 1536x256 bf16
  u16*   qr     = (u16*)(ws + off); off += 1228800;
  u16*   qc     = (u16*)(ws + off); off += 1228800;
  float* krm    = (float*)(ws + off); off += 786432;
  float* kcm    = (float*)(ws + off); off += 786432;
  float* kr     = (float*)(ws + off); off += 786432;
  float* kc     = (float*)(ws + off); off += 786432;
  u16*   attnb  = (u16*)(ws + off); off += 1228800;  // attn as bf16

  // D0: dtype detection (flag=1 -> raw inputs are f32)
  detect_kernel<<<1, 64, 0, stream>>>((const u16*)in_b, flag);

  // P0: weights -> bf16 once
  prep_weights_kernel<<<192, 256, 0, stream>>>(in_w, out_w, Wbf, flag);

  // K0: key means (768 blocks, coalesced float2)
  means_kernel<<<dim3(384, 2), 256, 0, stream>>>(key_row, key_col, krm, kcm, flag);

  // K1: q_row + q_col merged (blockIdx.z selects), bf16 out
  mfma_proj3<2,1,0><<<dim3(38, 4, 2), 256, 0, stream>>>(
      query_row, query_col, Wbf, 0, 256, in_b, 0, 256, qr, qc,
      2400, kScale, 0, hg, flag);

  // K1: kr + kc merged, f32 out
  mfma_proj3<0,0,0><<<dim3(12, 4, 2), 256, 0, stream>>>(
      krm, kcm, Wbf, 512, 768, in_b, 512, 768, kr, kc,
      768, 1.f, 0, hg, flag);

  // Per head group: v-proj (X read once, all cols per block) -> softmax -> core
  for (int head0 = 0; head0 < 8; head0 += hg){
    int wb = 1024 + head0*32;
    if (hg == 8)
      vproj_kernel<4><<<1152, 256, 0, stream>>>(value, Wbf, wb, in_b, wb, v_slab, hg, flag);
    else if (hg == 4)
      vproj_kernel<2><<<1152, 256, 0, stream>>>(value, Wbf, wb, in_b, wb, v_slab, hg, flag);
    else if (hg == 2)
      vproj_kernel<1><<<1152, 256, 0, stream>>>(value, Wbf, wb, in_b, wb, v_slab, hg, flag);
    else
      mfma_proj3<2,1,3><<<dim3(1152, 1, 1), 256, 0, stream>>>(
          value, value, Wbf, 1024, 1024, in_b, wb, wb,
          v_slab, v_slab, 73728, 1.f, head0, hg, flag);
    attn_weights_kernel<<<dim3(10, 8*hg, 2), 64, 0, stream>>>(qr, kr, qc, kc, arow, acol, head0, hg);
    rcda_core_kernel<<<dim3(10 * 8 * hg), 256, 0, stream>>>(arow, acol, v_slab, attnb, head0, hg);
  }

  // K4: output projection from bf16 attn, remap (n,l) -> row l*8+n
  mfma_proj3<1,2,1><<<dim3(38, 4, 1), 256, 0, stream>>>(
      attnb, attnb, Wbf, 1280, 1280, out_b, 0, 0, d_out, d_out,
      2400, 1.f, 0, hg, flag);
}

// Round 6
// 344.907 us; speedup vs baseline: 1.1349x; 1.1349x over previous
//
#include <hip/hip_runtime.h>
#include <stdint.h>

typedef unsigned short u16;
typedef unsigned int   u32;
typedef __attribute__((ext_vector_type(8))) short bf16x8;
typedef __attribute__((ext_vector_type(4))) float f32x4;

static constexpr float kScale = 0.17677669529663687f; // HD^-0.5

// ---------- bf16 helpers (bf16 carried as u16) ----------
__device__ __forceinline__ float bfl(u32 dw){ union{u32 u; float f;} x; x.u = dw << 16;        return x.f; }
__device__ __forceinline__ float bfh(u32 dw){ union{u32 u; float f;} x; x.u = dw & 0xffff0000u; return x.f; }
__device__ __forceinline__ float bf2f(u16 v){ union{u32 u; float f;} x; x.u = ((u32)v) << 16;  return x.f; }
__device__ __forceinline__ u16  f2bf(float f){
  union{float f; u32 u;} x; x.f = f;
  u32 r = x.u + 0x7fffu + ((x.u >> 16) & 1u);  // RNE
  return (u16)(r >> 16);
}

// ---------------------------------------------------------------------------
// D0: dtype detect. flag=1 means "inputs are f32".
// ---------------------------------------------------------------------------
__global__ void detect_kernel(const u16* __restrict__ bias, int* __restrict__ flag){
  int tid = threadIdx.x;               // 64 threads
  u16 raw = bias[tid * 2];
  int big = (fabsf(bf2f(raw)) > 1e6f) ? 1 : 0;
  if ((raw & 0x7F80u) == 0x7F80u) big = 1;   // NaN/Inf bit pattern
  #pragma unroll
  for (int m = 1; m < 64; m <<= 1) big |= __shfl_xor(big, m);
  if (tid == 0) *flag = big;
}

// ---------------------------------------------------------------------------
// P0+K0 merged: blocks [0,192) convert weights to bf16; blocks [192,960)
// compute key means. Both depend only on flag -> one launch, better fill.
// ---------------------------------------------------------------------------
__global__ __launch_bounds__(256) void prep_means_kernel(
    const void* __restrict__ in_w, const void* __restrict__ out_w,
    u16* __restrict__ Wbf,
    const void* __restrict__ key_row, const void* __restrict__ key_col,
    float* __restrict__ krm, float* __restrict__ kcm,
    const int* __restrict__ flag){
  const bool isf32 = (*flag != 0);
  int bx = blockIdx.x;
  int tid = threadIdx.x;

  if (bx < 192){
    // ---- prep weights: Wbf rows 0..1279 = in_proj, 1280..1535 = out_proj
    int idx = bx * 256 + tid;
    size_t off = (size_t)idx * 8;
    const size_t IN_ELEMS = (size_t)1280 * 256;
    bool isout = off >= IN_ELEMS;
    const void* src = isout ? out_w : in_w;
    size_t soff = isout ? off - IN_ELEMS : off;
    u16 xl[8];
    if (isf32){
      const float* p = (const float*)src + soff;
      float4 f0 = *(const float4*)p;
      float4 f1 = *(const float4*)(p + 4);
      xl[0]=f2bf(f0.x); xl[1]=f2bf(f0.y); xl[2]=f2bf(f0.z); xl[3]=f2bf(f0.w);
      xl[4]=f2bf(f1.x); xl[5]=f2bf(f1.y); xl[6]=f2bf(f1.z); xl[7]=f2bf(f1.w);
    } else {
      *(uint4*)xl = *(const uint4*)((const u16*)src + soff);
    }
    *(uint4*)(Wbf + off) = *(uint4*)xl;
    return;
  }

  // ---- means: 768 blocks, 2 rows/block, 2 cols/thread
  int bm  = bx - 192;                 // 0..767
  int mb  = bm % 384;
  int sel = bm / 384;                 // 0: krm, 1: kcm
  int r2  = tid >> 7;
  int cc  = (tid & 127) * 2;
  int row = mb * 2 + r2;              // 0..767 (= n*96 + rw)
  int n   = row / 96;
  int rw  = row - n*96;

  size_t base, stride;
  const void* src;
  float* dst;
  if (sel == 0){                // krm: mean over h; rw = w
    src    = key_row;
    base   = ((size_t)(n*96)*96 + rw)*256 + cc;
    stride = (size_t)96*256;
    dst    = krm + (size_t)row*256 + cc;
  } else {                      // kcm: mean over w; rw = h
    src    = key_col;
    base   = ((size_t)(n*96) + rw)*(size_t)(96*256) + cc;
    stride = 256;
    dst    = kcm + (size_t)row*256 + cc;
  }

  float a0 = 0.f, a1 = 0.f;
  if (isf32){
    const float* p = (const float*)src + base;
    #pragma unroll 4
    for (int t = 0; t < 96; t++){
      float2 f = *(const float2*)(p + t*stride);
      a0 += f.x; a1 += f.y;
    }
  } else {
    const u16* p = (const u16*)src + base;
    #pragma unroll 4
    for (int t = 0; t < 96; t++){
      u32 u = *(const u32*)(p + t*stride);
      a0 += bfl(u); a1 += bfh(u);
    }
  }
  dst[0] = a0 * (1.f/96.f);
  dst[1] = a1 * (1.f/96.f);
}

// ---------------------------------------------------------------------------
// Shared projection core (round-2 proven structure): 64x64 tile, 4 waves,
// 8 K-chunks, single-buffer LDS, 2 barriers/chunk, W from bf16 Wbf.
// omap: 0 row-major, 1 out-proj remap, 3 v-proj transposed slab.
// obf: 0 f32 out, 1 bf16 out. All control args are block-uniform.
// ---------------------------------------------------------------------------
__device__ __forceinline__ void proj_core(
    const void* __restrict__ Xv, bool xf32,
    const u16* __restrict__ Wbf, int wrow0, int wrel_add,
    const void* __restrict__ Bv, bool bvf32, int boff,
    void* __restrict__ Yv, int obf, int omap,
    int m0, int j0, int M, float scale, int hg,
    u16* __restrict__ Xs, u16* __restrict__ Ws, u16* __restrict__ stile){
  int tid = threadIdx.x;
  int wv  = tid >> 6;
  int ln  = tid & 63;
  int l15 = ln & 15;
  int quad = ln >> 4;
  int mh  = wv & 1;
  int nh  = wv >> 1;

  int srow = tid >> 2;          // 0..63 staging row
  int sko  = (tid & 3) * 8;     // 0,8,16,24

  f32x4 acc[2][2] = {{{0.f,0.f,0.f,0.f},{0.f,0.f,0.f,0.f}},
                     {{0.f,0.f,0.f,0.f},{0.f,0.f,0.f,0.f}}};

  int gm = m0 + srow;
  int wrel = j0 + srow;
  if (omap == 3){ wrel += wrel_add; if (wrel > 255) wrel = 255; }
  const u16* wsrc = Wbf + (size_t)(wrow0 + wrel)*256 + sko;

  for (int p = 0; p < 8; p++){
    int k0 = p * 32;
    u16 xl[8];
    if (gm < M){
      size_t xoff = (size_t)gm*256 + k0 + sko;
      if (xf32){
        const float* xp = (const float*)Xv + xoff;
        float4 f0 = *(const float4*)xp;
        float4 f1 = *(const float4*)(xp + 4);
        xl[0]=f2bf(f0.x); xl[1]=f2bf(f0.y); xl[2]=f2bf(f0.z); xl[3]=f2bf(f0.w);
        xl[4]=f2bf(f1.x); xl[5]=f2bf(f1.y); xl[6]=f2bf(f1.z); xl[7]=f2bf(f1.w);
      } else {
        *(uint4*)xl = *(const uint4*)((const u16*)Xv + xoff);
      }
    } else {
      #pragma unroll
      for (int i = 0; i < 8; i++) xl[i] = 0;
    }
    uint4 wl = *(const uint4*)(wsrc + k0);     // bf16 W: pure copy
    __syncthreads();
    *(uint4*)(Xs + srow*40 + sko) = *(uint4*)xl;
    *(uint4*)(Ws + srow*40 + sko) = wl;
    __syncthreads();

    bf16x8 a0 = *(const bf16x8*)(Xs + (mh*32 +      l15)*40 + quad*8);
    bf16x8 a1 = *(const bf16x8*)(Xs + (mh*32 + 16 + l15)*40 + quad*8);
    bf16x8 b0 = *(const bf16x8*)(Ws + (nh*32 +      l15)*40 + quad*8);
    bf16x8 b1 = *(const bf16x8*)(Ws + (nh*32 + 16 + l15)*40 + quad*8);
    acc[0][0] = __builtin_amdgcn_mfma_f32_16x16x32_bf16(a0, b0, acc[0][0], 0,0,0);
    acc[0][1] = __builtin_amdgcn_mfma_f32_16x16x32_bf16(a0, b1, acc[0][1], 0,0,0);
    acc[1][0] = __builtin_amdgcn_mfma_f32_16x16x32_bf16(a1, b0, acc[1][0], 0,0,0);
    acc[1][1] = __builtin_amdgcn_mfma_f32_16x16x32_bf16(a1, b1, acc[1][1], 0,0,0);
  }

  // bias per tj (col depends only on tj, l15)
  float bv[2];
  #pragma unroll
  for (int tj = 0; tj < 2; tj++){
    int bidx = j0 + nh*32 + tj*16 + l15;
    if (omap == 3 && bidx > hg*32 - 1) bidx = hg*32 - 1;  // clamped never stored
    bv[tj] = bvf32 ? ((const float*)Bv)[boff + bidx] : bf2f(((const u16*)Bv)[boff + bidx]);
  }

  if (omap == 3){
    __syncthreads();
    #pragma unroll
    for (int ti = 0; ti < 2; ti++)
      #pragma unroll
      for (int tj = 0; tj < 2; tj++)
        #pragma unroll
        for (int reg = 0; reg < 4; reg++)
          stile[(mh*32 + ti*16 + quad*4 + reg)*66 + nh*32 + tj*16 + l15] =
              f2bf(scale * (acc[ti][tj][reg] + bv[tj]));
    __syncthreads();
    int hw_i = tid & 63;
    int m    = m0 + hw_i;
    int nn   = m / 9216;
    int hwin = m - nn*9216;
    int hh   = hwin / 96, ww = hwin - hh*96;
    #pragma unroll
    for (int e = 0; e < 16; e++){
      int d_col = (tid >> 6) * 16 + e;   // 0..63
      int col   = j0 + d_col;
      if (col < hg*32){
        int gsv = nn*hg + (col >> 5), d = col & 31;
        ((u16*)Yv)[ (((size_t)gsv*96 + hh)*32 + d)*96 + ww ] = stile[hw_i*66 + d_col];
      }
    }
    return;
  }

  #pragma unroll
  for (int ti = 0; ti < 2; ti++)
    #pragma unroll
    for (int tj = 0; tj < 2; tj++)
      #pragma unroll
      for (int reg = 0; reg < 4; reg++){
        int m = m0 + mh*32 + ti*16 + quad*4 + reg;
        if (m >= M) continue;
        int col = j0 + nh*32 + tj*16 + l15;
        float vval = scale * (acc[ti][tj][reg] + bv[tj]);
        int orow = (omap == 1) ? ((m % 300)*8 + (m / 300)) : m;
        size_t oidx = (size_t)orow*256 + col;
        if (obf == 1) ((u16*)Yv)[oidx] = f2bf(vval);
        else          ((float*)Yv)[oidx] = vval;
      }
}

// ---------------------------------------------------------------------------
// K1 wrapper (compile-time specialization; used for out-proj and hg<8 paths).
// XF: 0 = X ws f32, 1 = X ws bf16, 2 = X raw input (dtype per flag).
// OBF: 0 f32 out, 1 bf16 out, 2 dtype-per-flag out.
// ---------------------------------------------------------------------------
template<int XF, int OBF, int OMAP>
__global__ __launch_bounds__(256) void mfma_proj3(
    const void* __restrict__ Xv0, const void* __restrict__ Xv1,
    const u16* __restrict__ Wbf, int wr00, int wr01,
    const void* __restrict__ Bv, int bo0, int bo1,
    void* __restrict__ Yv0, void* __restrict__ Yv1,
    int M, float scale, int head0, int hg,
    const int* __restrict__ flag){
  __shared__ __align__(16) u16 Xs[64*40];
  __shared__ __align__(16) u16 Ws[64*40];
  __shared__ __align__(16) u16 stile[(OMAP==3) ? 64*66 : 64];
  const bool isf32 = (*flag != 0);
  const bool xf32  = (XF == 0) || (XF == 2 && isf32);
  const int  obf   = (OBF == 2) ? (isf32 ? 0 : 1) : OBF;
  proj_core(blockIdx.z ? Xv1 : Xv0, xf32,
            Wbf, blockIdx.z ? wr01 : wr00, head0*32,
            Bv, isf32, blockIdx.z ? bo1 : bo0,
            blockIdx.z ? Yv1 : Yv0, obf, OMAP,
            blockIdx.x*64, blockIdx.y*64, M, scale, hg,
            Xs, Ws, stile);
}

// ---------------------------------------------------------------------------
// MEGA projection launch (hg==8): one kernel covering three independent jobs:
//   blocks [0,4608):     v-proj   (dim 1152 m-tiles x 4 j-tiles, OMAP3)
//   blocks [4608,4912):  q-proj   (38 x 4 x 2, OMAP0, bf16 out)
//   blocks [4912,5008):  k-proj   (12 x 4 x 2, OMAP0, f32 out, X=means f32)
// Small jobs ride under v-proj's residency instead of serial 1-block/CU walls.
// v ordering preserved: same-X j-blocks stay 1152 apart -> same XCD L2.
// __launch_bounds__(256,8): pin VGPR<=64 so 8 blocks/CU (round-5 cliff lesson).
// ---------------------------------------------------------------------------
__global__ __launch_bounds__(256, 8) void mega_proj_kernel(
    const void* __restrict__ query_row, const void* __restrict__ query_col,
    const float* __restrict__ krm, const float* __restrict__ kcm,
    const void* __restrict__ value,
    const u16* __restrict__ Wbf, const void* __restrict__ in_b,
    u16* __restrict__ qr, u16* __restrict__ qc,
    float* __restrict__ kr, float* __restrict__ kc,
    u16* __restrict__ v_slab,
    const int* __restrict__ flag){
  __shared__ __align__(16) u16 Xs[64*40];
  __shared__ __align__(16) u16 Ws[64*40];
  __shared__ __align__(16) u16 stile[64*66];
  const bool isf32 = (*flag != 0);
  const int bx = blockIdx.x;

  if (bx < 4608){
    // v-proj: head0=0, hg=8, scale=1, M=73728
    int m0 = (bx % 1152) * 64;
    int j0 = (bx / 1152) * 64;
    proj_core(value, isf32, Wbf, 1024, 0, in_b, isf32, 1024,
              v_slab, 1, 3, m0, j0, 73728, 1.f, 8, Xs, Ws, stile);
  } else if (bx < 4912){
    int bq = bx - 4608;                 // 0..303
    int qx = bq % 38;
    int qy = (bq / 38) & 3;
    int qz = bq / 152;
    proj_core(qz ? query_col : query_row, isf32,
              Wbf, qz ? 256 : 0, 0, in_b, isf32, qz ? 256 : 0,
              qz ? (void*)qc : (void*)qr, 1, 0,
              qx*64, qy*64, 2400, kScale, 8, Xs, Ws, stile);
  } else {
    int bk = bx - 4912;                 // 0..95
    int kx = bk % 12;
    int ky = (bk / 12) & 3;
    int kz = bk / 48;
    proj_core(kz ? (const void*)kcm : (const void*)krm, true,
              Wbf, kz ? 768 : 512, 0, in_b, isf32, kz ? 768 : 512,
              kz ? (void*)kc : (void*)kr, 0, 0,
              kx*64, ky*64, 768, 1.f, 8, Xs, Ws, stile);
  }
}

// ---------------------------------------------------------------------------
// K2: attention weights. Single-wave blocks; grid (10 l-tiles x 30, gs, rc).
// ---------------------------------------------------------------------------
__global__ __launch_bounds__(64) void attn_weights_kernel(
    const u16* __restrict__ qr, const float* __restrict__ kr,
    const u16* __restrict__ qc, const float* __restrict__ kc,
    u16* __restrict__ arow, u16* __restrict__ acol,
    int head0, int hg){
  __shared__ float qs[30*32];
  int lt = blockIdx.x;                 // 0..9
  int gs = blockIdx.y;                 // n*hg + hr
  int n  = gs / hg;
  int head = head0 + (gs % hg);
  const u16*   q = blockIdx.z ? qc : qr;
  const float* k = blockIdx.z ? kc : kr;
  u16*         a = blockIdx.z ? acol : arow;
  int lane = threadIdx.x;
  int l0   = lt * 30;

  for (int i = lane; i < 960; i += 64){
    int li = i >> 5, d = i & 31;
    qs[i] = bf2f(q[((size_t)(n*300) + l0 + li)*256 + head*32 + d]);
  }

  bool has2 = (lane < 32);
  float k1[32], k2[32];
  {
    const float* kp = k + ((size_t)(n*96) + lane)*256 + head*32;
    #pragma unroll
    for (int d4 = 0; d4 < 8; d4++){
      float4 f = *(const float4*)(kp + d4*4);
      k1[d4*4+0]=f.x; k1[d4*4+1]=f.y; k1[d4*4+2]=f.z; k1[d4*4+3]=f.w;
    }
    int w2c = has2 ? (64 + lane) : 95;
    const float* kp2 = k + ((size_t)(n*96) + w2c)*256 + head*32;
    #pragma unroll
    for (int d4 = 0; d4 < 8; d4++){
      float4 f = *(const float4*)(kp2 + d4*4);
      k2[d4*4+0]=f.x; k2[d4*4+1]=f.y; k2[d4*4+2]=f.z; k2[d4*4+3]=f.w;
    }
  }
  __syncthreads();

  for (int li = 0; li < 30; li++){
    const float* qv = qs + li*32;
    float s1 = 0.f, s2 = 0.f;
    #pragma unroll
    for (int d4 = 0; d4 < 8; d4++){
      float4 f = *(const float4*)(qv + d4*4);
      s1 += f.x*k1[d4*4+0] + f.y*k1[d4*4+1] + f.z*k1[d4*4+2] + f.w*k1[d4*4+3];
      s2 += f.x*k2[d4*4+0] + f.y*k2[d4*4+1] + f.z*k2[d4*4+2] + f.w*k2[d4*4+3];
    }
    float m = fmaxf(s1, has2 ? s2 : -1e30f);
    #pragma unroll
    for (int mask = 1; mask < 64; mask <<= 1) m = fmaxf(m, __shfl_xor(m, mask));
    float e1 = __expf(s1 - m);
    float e2 = has2 ? __expf(s2 - m) : 0.f;
    float s  = e1 + e2;
    #pragma unroll
    for (int mask = 1; mask < 64; mask <<= 1) s += __shfl_xor(s, mask);
    float inv = 1.f / s;
    u16* dst = a + ((size_t)gs*300 + l0 + li)*96;
    dst[lane] = f2bf(e1 * inv);
    if (has2) dst[64 + lane] = f2bf(e2 * inv);
  }
}

// ---------------------------------------------------------------------------
// K3 (MFMA): attn[n][l][head*32+d] = sum_h acol[l,h] * (sum_w arow[l,w] V[h,w,d])
// Vt bf16 [gs][h(96)][d(32)][w(96)]. attn output bf16.
// ---------------------------------------------------------------------------
__global__ __launch_bounds__(256) void rcda_core_kernel(
    const u16* __restrict__ arow, const u16* __restrict__ acol,
    const u16* __restrict__ v, u16* __restrict__ attn, int head0, int hg){
  __shared__ __align__(16) u16 vt[4*32*104];   // 26624 B, w-stride 104
  __shared__ __align__(16) u16 aw[32*96];      // 6144 B
  __shared__ float cs[32*97];                  // 12416 B
  __shared__ float red[2*64*8];                // 4096 B

  int b   = blockIdx.x;
  int xcd = b & 7;
  int jj  = b >> 3;
  int lt  = jj % 10;
  int gg  = jj / 10;
  int gs  = gg*8 + xcd;
  int n   = gs / hg;
  int head = head0 + (gs % hg);
  int l0  = lt * 32;
  int tid = threadIdx.x;
  int wv  = tid >> 6;
  int ln  = tid & 63;
  int l15 = ln & 15;
  int quad = ln >> 4;
  int nt  = wv & 1;
  int hp  = wv >> 1;

  for (int i = tid; i < 384; i += 256){
    int row = i / 12, rem = i - row*12;
    int lc = l0 + row; if (lc > 299) lc = 299;
    *(uint4*)(aw + row*96 + rem*8) = *(const uint4*)(arow + ((size_t)gs*300 + lc)*96 + rem*8);
  }
  for (int i = tid; i < 3072; i += 256){
    int row = i / 96, col = i - row*96;
    int lc = l0 + row; if (lc > 299) lc = 299;
    cs[row*97 + col] = bf2f(acol[((size_t)gs*300 + lc)*96 + col]);
  }
  __syncthreads();

  bf16x8 afr[2][3];
  #pragma unroll
  for (int mt = 0; mt < 2; mt++)
    #pragma unroll
    for (int ks = 0; ks < 3; ks++)
      afr[mt][ks] = *(const bf16x8*)(aw + (mt*16 + l15)*96 + ks*32 + quad*8);

  f32x4 out[2] = {{0.f,0.f,0.f,0.f},{0.f,0.f,0.f,0.f}};
  const u16* vbase = v + (size_t)gs * 96*32*96;

  for (int cc = 0; cc < 24; cc++){
    __syncthreads();
    const uint4* gsrc = (const uint4*)(vbase + (size_t)cc * 4*32*96);
    #pragma unroll
    for (int it = 0; it < 6; it++){
      int i = tid + it*256;
      int row = i / 12, rem = i - row*12;
      *(uint4*)((char*)vt + row*208 + rem*16) = gsrc[i];
    }
    __syncthreads();

    #pragma unroll
    for (int hh = 0; hh < 2; hh++){
      int h = hp*2 + hh;
      bf16x8 bfr[3];
      #pragma unroll
      for (int ks = 0; ks < 3; ks++)
        bfr[ks] = *(const bf16x8*)(vt + (h*32 + nt*16 + l15)*104 + ks*32 + quad*8);
      int habs = cc*4 + h;
      #pragma unroll
      for (int mt = 0; mt < 2; mt++){
        f32x4 t = {0.f,0.f,0.f,0.f};
        t = __builtin_amdgcn_mfma_f32_16x16x32_bf16(afr[mt][0], bfr[0], t, 0,0,0);
        t = __builtin_amdgcn_mfma_f32_16x16x32_bf16(afr[mt][1], bfr[1], t, 0,0,0);
        t = __builtin_amdgcn_mfma_f32_16x16x32_bf16(afr[mt][2], bfr[2], t, 0,0,0);
        #pragma unroll
        for (int reg = 0; reg < 4; reg++){
          float sc = cs[(mt*16 + quad*4 + reg)*97 + habs];
          out[mt][reg] += sc * t[reg];
        }
      }
    }
  }

  __syncthreads();
  if (hp == 1){
    float* r = red + ((size_t)(nt*64 + ln))*8;
    #pragma unroll
    for (int mt = 0; mt < 2; mt++)
      #pragma unroll
      for (int reg = 0; reg < 4; reg++) r[mt*4 + reg] = out[mt][reg];
  }
  __syncthreads();
  if (hp == 0){
    const float* r = red + ((size_t)(nt*64 + ln))*8;
    #pragma unroll
    for (int mt = 0; mt < 2; mt++){
      #pragma unroll
      for (int reg = 0; reg < 4; reg++){
        int l = l0 + mt*16 + quad*4 + reg;
        if (l < 300)
          attn[((size_t)(n*300) + l)*256 + head*32 + nt*16 + l15] =
              f2bf(out[mt][reg] + r[mt*4 + reg]);
      }
    }
  }
}

// ---------------------------------------------------------------------------
// Workspace: flag(256B) | Vt_slab | arow | acol | Wbf | qr | qc | krm | kcm |
//            kr | kc | attn_bf16
// need(hg) = hg*5,640,192 + 7,618,816 bytes
// ---------------------------------------------------------------------------
extern "C" void kernel_launch(void* const* d_in, const int* in_sizes, int n_in,
                              void* d_out, int out_size, void* d_ws, size_t ws_size,
                              hipStream_t stream){
  const void* query_row = d_in[0];
  const void* query_col = d_in[1];
  const void* key_row   = d_in[2];
  const void* key_col   = d_in[3];
  const void* value     = d_in[4];
  const void* in_w      = d_in[5];
  const void* in_b      = d_in[6];
  const void* out_w     = d_in[7];
  const void* out_b     = d_in[8];

  int hg = 1;
  {
    const size_t fixed = 7618816, per = 5640192;
    if      (ws_size >= fixed + 8*per) hg = 8;
    else if (ws_size >= fixed + 4*per) hg = 4;
    else if (ws_size >= fixed + 2*per) hg = 2;
    else                               hg = 1;
  }

  char* ws = (char*)d_ws;
  int*  flag = (int*)ws;
  size_t SV = (size_t)hg * 8 * 9216 * 32 * 2;  // Vt slab bf16
  size_t SA = (size_t)hg * 8 * 300 * 96 * 2;   // a slab bf16
  size_t off = 256;
  u16*   v_slab = (u16*)(ws + off); off += SV;
  u16*   arow   = (u16*)(ws + off); off += SA;
  u16*   acol   = (u16*)(ws + off); off += SA;
  u16*   Wbf    = (u16*)(ws + off); off += 786432;   // 1536x256 bf16
  u16*   qr     = (u16*)(ws + off); off += 1228800;
  u16*   qc     = (u16*)(ws + off); off += 1228800;
  float* krm    = (float*)(ws + off); off += 786432;
  float* kcm    = (float*)(ws + off); off += 786432;
  float* kr     = (float*)(ws + off); off += 786432;
  float* kc     = (float*)(ws + off); off += 786432;
  u16*   attnb  = (u16*)(ws + off); off += 1228800;  // attn as bf16

  // D0: dtype detection (flag=1 -> raw inputs are f32)
  detect_kernel<<<1, 64, 0, stream>>>((const u16*)in_b, flag);

  // P0+K0: weights->bf16 and key means in one launch
  prep_means_kernel<<<960, 256, 0, stream>>>(in_w, out_w, Wbf,
                                             key_row, key_col, krm, kcm, flag);

  if (hg == 8){
    // One mega launch: v-proj + q-proj + k-proj (independent jobs)
    mega_proj_kernel<<<5008, 256, 0, stream>>>(
        query_row, query_col, krm, kcm, value, Wbf, in_b,
        qr, qc, kr, kc, v_slab, flag);
    attn_weights_kernel<<<dim3(10, 64, 2), 64, 0, stream>>>(qr, kr, qc, kc, arow, acol, 0, 8);
    rcda_core_kernel<<<dim3(640), 256, 0, stream>>>(arow, acol, v_slab, attnb, 0, 8);
  } else {
    // Fallback: round-2 proven sequence
    mfma_proj3<2,1,0><<<dim3(38, 4, 2), 256, 0, stream>>>(
        query_row, query_col, Wbf, 0, 256, in_b, 0, 256, qr, qc,
        2400, kScale, 0, hg, flag);
    mfma_proj3<0,0,0><<<dim3(12, 4, 2), 256, 0, stream>>>(
        krm, kcm, Wbf, 512, 768, in_b, 512, 768, kr, kc,
        768, 1.f, 0, hg, flag);
    for (int head0 = 0; head0 < 8; head0 += hg){
      int gy = (hg*32 + 63) / 64;
      int wb = 1024 + head0*32;
      mfma_proj3<2,1,3><<<dim3(1152, gy, 1), 256, 0, stream>>>(
          value, value, Wbf, 1024, 1024, in_b, wb, wb,
          v_slab, v_slab, 73728, 1.f, head0, hg, flag);
      attn_weights_kernel<<<dim3(10, 8*hg, 2), 64, 0, stream>>>(qr, kr, qc, kc, arow, acol, head0, hg);
      rcda_core_kernel<<<dim3(10 * 8 * hg), 256, 0, stream>>>(arow, acol, v_slab, attnb, head0, hg);
    }
  }

  // K4: output projection from bf16 attn, remap (n,l) -> row l*8+n
  mfma_proj3<1,2,1><<<dim3(38, 4, 1), 256, 0, stream>>>(
      attnb, attnb, Wbf, 1280, 1280, out_b, 0, 0, d_out, d_out,
      2400, 1.f, 0, hg, flag);
}